// Round 12
// baseline (7613.927 us; speedup 1.0000x reference)
//
#include <hip/hip_runtime.h>
#include <math.h>

#define HID    512
#define NIN    256
#define TIN    4096
#define NSTEP  1023
#define NEVAL  (NSTEP*4)
#define NWG    16
#define SLICE  32          // state elements owned per WG
#define NTH    1024
#define ET     16          // evals per gu2 block

// searchsorted(linspace(0,1,4096), t, side='left') clipped to [0, 4095]
__device__ __forceinline__ int zoh_index(float t) {
  const float delta = 1.0f / 4095.0f;
  int lo = 0, hi = TIN;
  while (lo < hi) {
    int mid = (lo + hi) >> 1;
    float g = (float)mid * delta;
    if (g < t) lo = mid + 1; else hi = mid;
  }
  return lo > TIN - 1 ? TIN - 1 : lo;
}

// Tiled gu precompute (r11-proven, spill-free): block (et, rb) = 16 evals x 256 rows.
__global__ void __launch_bounds__(256)
gu2_kernel(const float* __restrict__ I_seq, const float* __restrict__ t_save,
           const float* __restrict__ U_tau, const float* __restrict__ b_tau,
           const float* __restrict__ U_f,   const float* __restrict__ b_f,
           float* __restrict__ gu)
{
  __shared__ float Ild[ET][NIN];
  __shared__ int idxs[ET];
  const int tid = threadIdx.x;
  const int e0 = blockIdx.x * ET;
  const int rb = blockIdx.y;                  // 0..3 -> rows [256rb, +256)

  if (tid < ET) {
    const int e = e0 + tid;
    const int ec = e < NEVAL ? e : (NEVAL - 1);
    const int n = ec >> 2, s = ec & 3;
    const float t0 = t_save[n], t1 = t_save[n + 1];
    const float dt = t1 - t0;
    const float third = 1.0f / 3.0f;
    float t;
    if      (s == 0) t = t0;
    else if (s == 1) t = t0 + dt * third;
    else if (s == 2) t = t0 + (dt * 2.0f) * third;
    else             t = t1;
    idxs[tid] = zoh_index(t);
  }
  __syncthreads();
  #pragma unroll
  for (int q = 0; q < 4; ++q) {               // 1024 float4 slots = 16 evals x 64
    const int li = q * 256 + tid;
    const int ee = li >> 6, c4 = li & 63;
    ((float4*)&Ild[ee][0])[c4] = ((const float4*)(I_seq + (size_t)idxs[ee] * NIN))[c4];
  }
  __syncthreads();

  const int row = rb * 256 + tid;             // 0..1023 stacked [U_tau; U_f]
  const float* Urow = (row < HID) ? (U_tau + (size_t)row * NIN)
                                  : (U_f + (size_t)(row - HID) * NIN);
  const float bb = (row < HID) ? b_tau[row] : b_f[row - HID];
  const float4* Uv = (const float4*)Urow;

  float acc[ET];
  #pragma unroll
  for (int k = 0; k < ET; ++k) acc[k] = 0.f;

  for (int c = 0; c < NIN / 4; c += 4) {      // 16 outer iters
    const float4 u0 = Uv[c + 0], u1 = Uv[c + 1], u2 = Uv[c + 2], u3 = Uv[c + 3];
    #pragma unroll
    for (int k = 0; k < ET; ++k) {
      const float4* iv = (const float4*)&Ild[k][0];
      const float4 x0 = iv[c + 0], x1 = iv[c + 1], x2 = iv[c + 2], x3 = iv[c + 3];
      float a = acc[k];
      a = fmaf(u0.x, x0.x, a); a = fmaf(u0.y, x0.y, a);
      a = fmaf(u0.z, x0.z, a); a = fmaf(u0.w, x0.w, a);
      a = fmaf(u1.x, x1.x, a); a = fmaf(u1.y, x1.y, a);
      a = fmaf(u1.z, x1.z, a); a = fmaf(u1.w, x1.w, a);
      a = fmaf(u2.x, x2.x, a); a = fmaf(u2.y, x2.y, a);
      a = fmaf(u2.z, x2.z, a); a = fmaf(u2.w, x2.w, a);
      a = fmaf(u3.x, x3.x, a); a = fmaf(u3.y, x3.y, a);
      a = fmaf(u3.z, x3.z, a); a = fmaf(u3.w, x3.w, a);
      acc[k] = a;
    }
  }
  #pragma unroll
  for (int k = 0; k < ET; ++k) {
    const int e = e0 + k;
    if (e < NEVAL) gu[(size_t)e * 1024 + row] = acc[k] + bb;
  }
}

// 4-deep pipelined poll of ONE address, phases staggered ~RT/4 by s_sleep(8)
// (~213ns) at issue; the stagger persists through reissues (slot k reissued when
// slot k returns). Sampling interval ~RT/4 -> detect phase-lag RT/2 -> RT/8.
// sc1 load observes agent-scope atomic stores (r11-proven correct). BOUNDED:
// 2048 iterations, then fall back to the rounds-2-11-proven atomic-load spin.
__device__ __forceinline__ unsigned long long poll4(
    const unsigned long long* p, unsigned tag) {
  unsigned long long v0, v1, v2, v3;
  asm volatile("global_load_dwordx2 %0, %1, off sc1" : "=&v"(v0) : "v"(p) : "memory");
  __builtin_amdgcn_s_sleep(8);
  asm volatile("global_load_dwordx2 %0, %1, off sc1" : "=&v"(v1) : "v"(p) : "memory");
  __builtin_amdgcn_s_sleep(8);
  asm volatile("global_load_dwordx2 %0, %1, off sc1" : "=&v"(v2) : "v"(p) : "memory");
  __builtin_amdgcn_s_sleep(8);
  asm volatile("global_load_dwordx2 %0, %1, off sc1" : "=&v"(v3) : "v"(p) : "memory");
  #pragma unroll 1
  for (int it = 0; it < 2048; ++it) {
    asm volatile("s_waitcnt vmcnt(3)" ::: "memory");
    __builtin_amdgcn_sched_barrier(0);
    if ((unsigned)(v0 >> 32) == tag) { asm volatile("s_waitcnt vmcnt(0)" ::: "memory"); return v0; }
    asm volatile("global_load_dwordx2 %0, %1, off sc1" : "=&v"(v0) : "v"(p) : "memory");
    asm volatile("s_waitcnt vmcnt(3)" ::: "memory");
    __builtin_amdgcn_sched_barrier(0);
    if ((unsigned)(v1 >> 32) == tag) { asm volatile("s_waitcnt vmcnt(0)" ::: "memory"); return v1; }
    asm volatile("global_load_dwordx2 %0, %1, off sc1" : "=&v"(v1) : "v"(p) : "memory");
    asm volatile("s_waitcnt vmcnt(3)" ::: "memory");
    __builtin_amdgcn_sched_barrier(0);
    if ((unsigned)(v2 >> 32) == tag) { asm volatile("s_waitcnt vmcnt(0)" ::: "memory"); return v2; }
    asm volatile("global_load_dwordx2 %0, %1, off sc1" : "=&v"(v2) : "v"(p) : "memory");
    asm volatile("s_waitcnt vmcnt(3)" ::: "memory");
    __builtin_amdgcn_sched_barrier(0);
    if ((unsigned)(v3 >> 32) == tag) { asm volatile("s_waitcnt vmcnt(0)" ::: "memory"); return v3; }
    asm volatile("global_load_dwordx2 %0, %1, off sc1" : "=&v"(v3) : "v"(p) : "memory");
  }
  asm volatile("s_waitcnt vmcnt(0)" ::: "memory");
  unsigned long long pk;
  do {
    pk = __hip_atomic_load(p, __ATOMIC_RELAXED, __HIP_MEMORY_SCOPE_AGENT);
  } while ((unsigned)(pk >> 32) != tag);
  return pk;
}

// Persistent cooperative scan: EXACT round-3 structure (16 WGs x 1024, dense
// packed (tag,value) words at the LLC, parity ping-pong, single xsp buffer,
// two barriers, pre[] funnel, wave-0 coalesced release). Only the consumer
// poll is replaced by poll4 (same load instruction class, higher cadence).
__global__ void __launch_bounds__(NTH, 1)
ltc_main(const float* __restrict__ x0, const float* __restrict__ t_save,
         const float* __restrict__ W_tau, const float* __restrict__ tau0,
         const float* __restrict__ W_f,
         const float* __restrict__ gu,
         unsigned long long* xslot,          // [2][512] packed (tag, value)
         float* __restrict__ out)
{
  const int wg   = blockIdx.x;
  const int tid  = threadIdx.x;
  const int row  = tid >> 4;    // 0..63
  const int seg  = tid & 15;    // 0..15, 32 columns each
  const int base = wg * SLICE;

  const float* wrow = ((row < SLICE)
      ? (W_tau + (size_t)(base + row) * HID)
      : (W_f   + (size_t)(base + row - SLICE) * HID)) + seg * 32;

  float4 w4[8];
  #pragma unroll
  for (int t = 0; t < 8; ++t) w4[t] = ((const float4*)wrow)[t];

  __shared__ float xsp[16 * 36];   // stride-36: <=2-way conflicts (free)
  __shared__ float pre[64];

  float y0 = 0.f, k1 = 0.f, k2 = 0.f, k3 = 0.f, curx = 0.f, tz = 0.f;
  if (tid < SLICE) {
    y0   = x0[base + tid];
    curx = y0;
    tz   = tau0[base + tid];
    out[base + tid] = y0;            // out[0] = x0
  }

  for (int n = 0; n < NSTEP; ++n) {
    const float t0 = t_save[n], t1 = t_save[n + 1];
    const float dt = t1 - t0;
    #pragma unroll
    for (int s = 0; s < 4; ++s) {
      const int e = (n << 2) + s;

      // gu loads issued first: latency hides under the poll below
      float gt = 0.f, gf = 0.f;
      if (tid < SLICE) {
        const float* g = gu + (size_t)e * 1024 + base + tid;
        gt = g[0];
        gf = g[512];
      }

      // ---- acquire x_e: 4-deep pipelined poll, fill LDS ----
      if (tid < HID) {
        float v;
        if (e == 0) {
          v = x0[tid];
        } else {
          const unsigned long long pk =
              poll4(xslot + (size_t)(e & 1) * HID + tid, (unsigned)e);
          v = __uint_as_float((unsigned)pk);
        }
        xsp[(tid >> 5) * 36 + (tid & 31)] = v;
      }
      __syncthreads();

      // ---- matvec: 32 MACs/thread from VGPR weights + LDS x ----
      float acc = 0.f;
      #pragma unroll
      for (int t = 0; t < 8; ++t) {
        const float4 xv = *reinterpret_cast<const float4*>(&xsp[seg * 36 + 4 * t]);
        acc = fmaf(w4[t].x, xv.x, acc);
        acc = fmaf(w4[t].y, xv.y, acc);
        acc = fmaf(w4[t].z, xv.z, acc);
        acc = fmaf(w4[t].w, xv.w, acc);
      }
      acc += __shfl_xor(acc, 1);
      acc += __shfl_xor(acc, 2);
      acc += __shfl_xor(acc, 4);
      acc += __shfl_xor(acc, 8);
      if ((tid & 15) == 0) pre[row] = acc;
      __syncthreads();

      // ---- elementwise + RK4; wave-0 coalesced release (r3-proven) ----
      if (tid < SLICE) {
        const float zt  = pre[tid] + gt;
        const float zf  = pre[SLICE + tid] + gf;
        const float ez  = __expf(-fabsf(zt));
        const float sp  = fmaxf(zt, 0.f) + __logf(1.f + ez);
        const float tau = tz + sp;
        const float ef  = __expf(-2.f * fabsf(zf));
        const float th  = (1.f - ef) * __builtin_amdgcn_rcpf(1.f + ef);
        const float f   = (zf >= 0.f) ? th : -th;
        const float d   = f - curx * __builtin_amdgcn_rcpf(tau);
        float xnew;
        if      (s == 0) { k1 = d; xnew = y0 + dt * k1 * (1.0f/3.0f); }
        else if (s == 1) { k2 = d; xnew = y0 + dt * (k2 - k1 * (1.0f/3.0f)); }
        else if (s == 2) { k3 = d; xnew = y0 + dt * (k1 - k2 + k3); }
        else             { xnew = y0 + (k1 + 3.0f * (k2 + k3) + d) * dt * 0.125f; y0 = xnew; }
        curx = xnew;
        const unsigned long long pk =
            ((unsigned long long)(unsigned)(e + 1) << 32) |
            (unsigned long long)__float_as_uint(xnew);
        __hip_atomic_store(xslot + (size_t)((e + 1) & 1) * HID + base + tid, pk,
                           __ATOMIC_RELAXED, __HIP_MEMORY_SCOPE_AGENT);
        if (s == 3) out[(size_t)(n + 1) * HID + base + tid] = xnew;  // after release
      }
      // no trailing barrier: ordered by the two barriers above (r3-proven)
    }
  }
}

extern "C" void kernel_launch(void* const* d_in, const int* in_sizes, int n_in,
                              void* d_out, int out_size, void* d_ws, size_t ws_size,
                              hipStream_t stream) {
  const float* x0     = (const float*)d_in[0];
  const float* I_seq  = (const float*)d_in[1];
  const float* t_save = (const float*)d_in[2];
  const float* W_tau  = (const float*)d_in[3];
  const float* U_tau  = (const float*)d_in[4];
  const float* b_tau  = (const float*)d_in[5];
  const float* tau0   = (const float*)d_in[6];
  const float* W_f    = (const float*)d_in[7];
  const float* U_f    = (const float*)d_in[8];
  const float* b_f    = (const float*)d_in[9];
  float* out = (float*)d_out;

  char* ws = (char*)d_ws;
  unsigned long long* xslot = (unsigned long long*)(ws + 1024);  // [2][512] = 8KB
  float* gu = (float*)(ws + 16384);                              // ~16.8MB

  // zero tags every call -> replay-safe, first-call-safe (tag 0 never matches)
  hipMemsetAsync(xslot, 0, 2 * HID * sizeof(unsigned long long), stream);
  gu2_kernel<<<dim3((NEVAL + ET - 1) / ET, 4), 256, 0, stream>>>(
      I_seq, t_save, U_tau, b_tau, U_f, b_f, gu);

  void* args[] = { (void*)&x0, (void*)&t_save, (void*)&W_tau, (void*)&tau0, (void*)&W_f,
                   (void*)&gu, (void*)&xslot, (void*)&out };
  hipLaunchCooperativeKernel((const void*)ltc_main, dim3(NWG), dim3(NTH),
                             args, 0, stream);
}